// Round 8
// baseline (500.033 us; speedup 1.0000x reference)
//
#include <hip/hip_runtime.h>

typedef float    v2f __attribute__((ext_vector_type(2)));
typedef unsigned v2u __attribute__((ext_vector_type(2)));
typedef _Float16 h2  __attribute__((ext_vector_type(2)));

// Problem constants (from reference)
constexpr int CB   = 128;
constexpr int CC   = 12;
constexpr int CL   = 2048;
constexpr int CK   = 8;
constexpr int CG   = 32;
constexpr int CNCP = 6;
constexpr int CND  = 8;
constexpr int HALO = 512;   // max tap reach = 4*128 (elements)
constexpr int BUF  = HALO + CL + HALO + 16;   // elements (even)
constexpr int BUFU = BUF / 2;                 // u32 (f16 pair) slots

#define H2(u) __builtin_bit_cast(h2, (u))
#if defined(__has_builtin)
#  if __has_builtin(__builtin_amdgcn_fdot2)
#    define FD(a,b,c) __builtin_amdgcn_fdot2((a),(b),(c),false)
#  endif
#endif
#ifndef FD
#  define FD(a,b,c) fmaf((float)(a).x,(float)(b).x, fmaf((float)(a).y,(float)(b).y,(c)))
#endif

// ---------------------------------------------------------------------------
// Transpose + f16-pack W: [pair][g*8+k][9] -> Wt u32[pair][g][jj*8+k],
// each u32 = half2(w[2jj], jj<4 ? w[2jj+1] : 0).
// ---------------------------------------------------------------------------
__global__ void transposeW16(const float* __restrict__ W, unsigned* __restrict__ Wt) {
    int t = blockIdx.x * blockDim.x + threadIdx.x;
    constexpr int total = CND * 2 * CG * CK * 5; // 20480
    if (t >= total) return;
    int jj = t % 5; int r = t / 5;
    int k = r % CK; r /= CK;
    int g = r % CG; int pair = r / CG;
    const float* src = W + ((size_t)(pair * (CG * CK)) + g * CK + k) * 9;
    const float wa = src[2 * jj];
    const float wb = (jj < 4) ? src[2 * jj + 1] : 0.f;
    h2 h; h.x = (_Float16)wa; h.y = (_Float16)wb;   // RNE
    Wt[(pair * CG + g) * 40 + jj * 8 + k] = __builtin_bit_cast(unsigned, h);
}

__device__ __forceinline__ float4 ld4(const float* p) { return *(const float4*)p; }

// Embed kernel index k in the 3 low mantissa bits (R11-proven).
__device__ __forceinline__ float packidx_s(float v, unsigned code) {
    unsigned u = __builtin_bit_cast(unsigned, v);
    u = (u & 0xFFFFFFF8u) | code;
    return __builtin_bit_cast(float, u);
}
__device__ __forceinline__ int lowbits(float v) {
    return (int)(__builtin_bit_cast(unsigned, v) & 7u);
}

// ---------------------------------------------------------------------------
// Ledger:
// R1 (440us): LDS scatter bins. R2 (924us, REV): LDS atomics slow.
// R3 (457us, REV): parity-split +8KB LDS -> 5 blocks/CU. R4 (425us):
// bins[9] dummy-row + loads-before-stores, thread-private columns.
// R5 (FAIL): XOR-column raced. R6 (437us, REV): unroll2 hurt occupancy.
// R7 (413us): tap-0 packed MUL kills 16 v_mov/iter.
// R8: f16 conv pipeline. v_pk_fma_f32 is HALF-rate (157TF = scalar rate);
//     v_dot2_f32_f16 does 2 MACs in ONE full-rate slot (f16 peak = 2x f32).
//     inp stored in LDS as f16 pairs (u32), weights prepacked half2
//     tap-pairs, conv = 80 dot2 + ~10 v_perm per p-iter vs 144 slots.
//     f32 accumulation via dot2's C operand. LDS 22016->15872 -> 8
//     blocks/CU (was 7). Select/bin/RSCAT structure unchanged from R7.
// ---------------------------------------------------------------------------
__global__ void __launch_bounds__(256)
hydra_fused(const float* __restrict__ X, const unsigned* __restrict__ Wt,
            const int* __restrict__ I, float* __restrict__ out)
{
    __shared__ unsigned inpU[BUFU];      // f16-pair staging (elem 2i, 2i+1)
    __shared__ float wavehist[4 * 16];
    __shared__ float bins[9][256];       // rows 0..7 per-thread bins, row 8 dummy
    const int tid = threadIdx.x;
    // XCD swizzle (R8-proven): 16 batches per XCD; pair varies fastest.
    const int blk  = blockIdx.x;
    const int x    = blk & 7;
    const int r    = blk >> 3;            // [0,1024)
    const int pair = r & 15;
    const int gq   = (r >> 4) & 3;
    const int b    = x * 16 + (r >> 6);
    const int di    = pair >> 1;
    const int diffi = pair & 1;
    const int D     = 1 << di;
    const int Lout  = CL - diffi;
    const float* __restrict__ Xb = X + (size_t)b * (CC * CL);

    // zero halos (u32 granularity): front elems [0,512) = u32 [0,256);
    // tail elems [HALO+CL, BUF) = u32 [1280, BUFU)
    for (int i = tid; i < HALO / 2; i += 256) inpU[i] = 0u;
    for (int i = (HALO + CL) / 2 + tid; i < BUFU; i += 256) inpU[i] = 0u;
    #pragma unroll
    for (int k2 = 0; k2 < 8; ++k2) bins[k2][tid] = 0.f;

    #pragma unroll 1
    for (int gi = 0; gi < 8; ++gi) {
        const int g = gq * 8 + gi;
        // ---- stage summed (and optionally diffed) row, f16-packed ----
        const int* __restrict__ Ig = I + (pair * CG + g) * CNCP;
        const int ch0 = Ig[0], ch1 = Ig[1], ch2 = Ig[2],
                  ch3 = Ig[3], ch4 = Ig[4], ch5 = Ig[5];
        const float* r0 = Xb + ch0 * CL; const float* r1 = Xb + ch1 * CL;
        const float* r2 = Xb + ch2 * CL; const float* r3 = Xb + ch3 * CL;
        const float* r4 = Xb + ch4 * CL; const float* r5 = Xb + ch5 * CL;

        #pragma unroll
        for (int cc = 0; cc < 2; ++cc) {
            const int pos = cc * 1024 + tid * 4;
            const float4 x0 = ld4(r0 + pos), x1 = ld4(r1 + pos), x2 = ld4(r2 + pos),
                         x3 = ld4(r3 + pos), x4 = ld4(r4 + pos), x5 = ld4(r5 + pos);
            float4 s;
            s.x = ((x0.x + x1.x) + (x2.x + x3.x)) + (x4.x + x5.x);
            s.y = ((x0.y + x1.y) + (x2.y + x3.y)) + (x4.y + x5.y);
            s.z = ((x0.z + x1.z) + (x2.z + x3.z)) + (x4.z + x5.z);
            s.w = ((x0.w + x1.w) + (x2.w + x3.w)) + (x4.w + x5.w);
            float4 o = s;
            if (diffi) {
                float s4;
                if (pos + 4 < CL)
                    s4 = ((r0[pos + 4] + r1[pos + 4]) + (r2[pos + 4] + r3[pos + 4]))
                         + (r4[pos + 4] + r5[pos + 4]);
                else
                    s4 = s.w; // => diff 0 at padding position 2047
                o = make_float4(s.y - s.x, s.z - s.y, s.w - s.z, s4 - s.w);
            }
            v2u val;
            val.x = __builtin_bit_cast(unsigned, __builtin_amdgcn_cvt_pkrtz(o.x, o.y));
            val.y = __builtin_bit_cast(unsigned, __builtin_amdgcn_cvt_pkrtz(o.z, o.w));
            *(v2u*)&inpU[(HALO + pos) / 2] = val;   // 8B aligned (pos%4==0)
        }
        __syncthreads();

        // ---- conv (f16 dot2) + packed-index select + LDS RMW bins ----
        const unsigned* __restrict__ Wg = Wt + (pair * CG + g) * 40;
        unsigned bnpack = 0;

        #pragma unroll 1
        for (int p = 0; p < 4; ++p) {
            const int l = p * 512 + tid * 2;          // even; positions l, l+1
            const unsigned* baseU = &inpU[(HALO + l) / 2];

            // assemble 10 half2 tap-pair operands (P* = pos l, Q* = pos l+1)
            unsigned p0v, p1v, p2v, p3v, p4v, q0v, q1v, q2v, q3v, q4v;
            if (di == 0) {
                const unsigned U0 = baseU[-2], U1 = baseU[-1], U2 = baseU[0],
                               U3 = baseU[1],  U4 = baseU[2];
                p0v = U0; p1v = U1; p2v = U2; p3v = U3; p4v = U4 & 0xFFFFu;
                q0v = __builtin_amdgcn_perm(U1, U0, 0x05040302u);
                q1v = __builtin_amdgcn_perm(U2, U1, 0x05040302u);
                q2v = __builtin_amdgcn_perm(U3, U2, 0x05040302u);
                q3v = __builtin_amdgcn_perm(U4, U3, 0x05040302u);
                q4v = U4 >> 16;
            } else {
                const int sD = D >> 1;               // u32 stride between taps
                const unsigned U0 = baseU[-4*sD], U1 = baseU[-3*sD], U2 = baseU[-2*sD],
                               U3 = baseU[-1*sD], U4 = baseU[0],     U5 = baseU[1*sD],
                               U6 = baseU[2*sD],  U7 = baseU[3*sD],  U8 = baseU[4*sD];
                p0v = __builtin_amdgcn_perm(U1, U0, 0x05040100u);
                p1v = __builtin_amdgcn_perm(U3, U2, 0x05040100u);
                p2v = __builtin_amdgcn_perm(U5, U4, 0x05040100u);
                p3v = __builtin_amdgcn_perm(U7, U6, 0x05040100u);
                p4v = U8 & 0xFFFFu;
                q0v = __builtin_amdgcn_perm(U1, U0, 0x07060302u);
                q1v = __builtin_amdgcn_perm(U3, U2, 0x07060302u);
                q2v = __builtin_amdgcn_perm(U5, U4, 0x07060302u);
                q3v = __builtin_amdgcn_perm(U7, U6, 0x07060302u);
                q4v = U8 >> 16;
            }

            float qx0, qx1, qx2, qx3, qx4, qx5, qx6, qx7;
            float qy0, qy1, qy2, qy3, qy4, qy5, qy6, qy7;
            #define KDO(K) { \
                const h2 w0 = H2(Wg[ 0 + K]), w1 = H2(Wg[ 8 + K]), \
                         w2 = H2(Wg[16 + K]), w3 = H2(Wg[24 + K]), \
                         w4 = H2(Wg[32 + K]); \
                const float aL = FD(H2(p0v), w0, FD(H2(p1v), w1, FD(H2(p2v), w2, \
                                 FD(H2(p3v), w3, FD(H2(p4v), w4, 0.f))))); \
                const float aR = FD(H2(q0v), w0, FD(H2(q1v), w1, FD(H2(q2v), w2, \
                                 FD(H2(q3v), w3, FD(H2(q4v), w4, 0.f))))); \
                qx##K = packidx_s(aL, K); qy##K = packidx_s(aR, K); }
            KDO(0) KDO(1) KDO(2) KDO(3) KDO(4) KDO(5) KDO(6) KDO(7)
            #undef KDO

            // scalar max3/min3 nests: 4 ops per tree
            const float mxx = fmaxf(fmaxf(fmaxf(fmaxf(qx0, qx1), qx2),
                                          fmaxf(fmaxf(qx3, qx4), qx5)),
                                    fmaxf(qx6, qx7));
            const float mxy = fmaxf(fmaxf(fmaxf(fmaxf(qy0, qy1), qy2),
                                          fmaxf(fmaxf(qy3, qy4), qy5)),
                                    fmaxf(qy6, qy7));
            const float mnx = fminf(fminf(fminf(fminf(qx0, qx1), qx2),
                                          fminf(fminf(qx3, qx4), qx5)),
                                    fminf(qx6, qx7));
            const float mny = fminf(fminf(fminf(fminf(qy0, qy1), qy2),
                                          fminf(fminf(qy3, qy4), qy5)),
                                    fminf(qy6, qy7));

            const int mi0 = lowbits(mxx), mi1 = lowbits(mxy);
            const int ni0 = lowbits(mnx), ni1 = lowbits(mny);

            float vx = mxx, vy = mxy;
            const bool v1ok = (l + 1) < Lout;
            if (!v1ok) vy = 0.f;   // +0.0 into a live bin is a no-op for the sum

            // Alias-free dual RMW, one LDS round-trip (R4-proven):
            // if mi0==mi1 fold vy into vx and send RMW #2 to dummy row 8.
            // Thread-private column tid -> no lane x lane races (R5 lesson).
            const bool eq = (mi0 == mi1);
            const float vxe = eq ? (vx + vy) : vx;
            const int   mi1p = eq ? 8 : mi1;
            float* p0 = &bins[mi0][tid];
            float* p1 = &bins[mi1p][tid];
            const float o0 = *p0;            // both loads precede both stores
            const float o1 = *p1;
            *p0 = o0 + vxe;
            *p1 = o1 + vy;
            bnpack += (1u << (ni0 * 4)) + (v1ok ? (1u << (ni1 * 4)) : 0u);
        }

        // ---- read back bins, re-zero ----
        float f0 = bins[0][tid], f1 = bins[1][tid],
              f2 = bins[2][tid], f3 = bins[3][tid],
              f4 = bins[4][tid], f5 = bins[5][tid],
              f6 = bins[6][tid], f7 = bins[7][tid];
        #pragma unroll
        for (int k2 = 0; k2 < 8; ++k2) bins[k2][tid] = 0.f;

        float h0 = (float)((bnpack >>  0) & 15), h1 = (float)((bnpack >>  4) & 15),
              h2v = (float)((bnpack >>  8) & 15), h3 = (float)((bnpack >> 12) & 15),
              h4 = (float)((bnpack >> 16) & 15), h5 = (float)((bnpack >> 20) & 15),
              h6 = (float)((bnpack >> 24) & 15), h7 = (float)((bnpack >> 28) & 15);

        // ---- reduce-scatter over 64 lanes (R10-proven, 10 shuffles/set) ----
        const int lane = tid & 63;
        const bool l5 = (lane & 32) != 0, l4 = (lane & 16) != 0, l3 = (lane & 8) != 0;

        #define RSCAT(q, v0, v1, v2, v3, v4, v5, v6, v7)                          \
            float q;                                                              \
            {                                                                     \
                float k0 = l5 ? v4 : v0, s0 = l5 ? v0 : v4;                       \
                float k1 = l5 ? v5 : v1, s1 = l5 ? v1 : v5;                       \
                float k2 = l5 ? v6 : v2, s2 = l5 ? v2 : v6;                       \
                float k3 = l5 ? v7 : v3, s3 = l5 ? v3 : v7;                       \
                k0 += __shfl_xor(s0, 32); k1 += __shfl_xor(s1, 32);               \
                k2 += __shfl_xor(s2, 32); k3 += __shfl_xor(s3, 32);               \
                float m0 = l4 ? k2 : k0, t0 = l4 ? k0 : k2;                       \
                float m1 = l4 ? k3 : k1, t1 = l4 ? k1 : k3;                       \
                m0 += __shfl_xor(t0, 16); m1 += __shfl_xor(t1, 16);               \
                q = l3 ? m1 : m0; float u = l3 ? m0 : m1;                         \
                q += __shfl_xor(u, 8);                                            \
                q += __shfl_xor(q, 4); q += __shfl_xor(q, 2);                     \
                q += __shfl_xor(q, 1);                                            \
            }
        RSCAT(qf, f0, f1, f2, f3, f4, f5, f6, f7)
        RSCAT(qc, h0, h1, h2v, h3, h4, h5, h6, h7)
        #undef RSCAT

        // lane holds totals for bin = 4*bit5 + 2*bit4 + bit3
        if ((lane & 7) == 0) {
            const int bin = (l5 ? 4 : 0) + (l4 ? 2 : 0) + (l3 ? 1 : 0);
            float* wh = wavehist + (tid >> 6) * 16;
            wh[bin]     = qf;
            wh[8 + bin] = qc;
        }
        __syncthreads();

        if (tid < 16) {
            const float s = wavehist[tid] + wavehist[16 + tid]
                          + wavehist[32 + tid] + wavehist[48 + tid];
            const int which = tid >> 3, k = tid & 7;
            out[(size_t)b * 8192 + ((pair * 2 + which) * CG + g) * CK + k] = s;
        }
    }
}

extern "C" void kernel_launch(void* const* d_in, const int* in_sizes, int n_in,
                              void* d_out, int out_size, void* d_ws, size_t ws_size,
                              hipStream_t stream)
{
    const float* X = (const float*)d_in[0];
    const float* W = (const float*)d_in[1];
    const int*   I = (const int*)d_in[2];
    float* out = (float*)d_out;
    unsigned* Wt = (unsigned*)d_ws;   // 20480 u32 = 80 KiB scratch

    transposeW16<<<dim3((20480 + 255) / 256), dim3(256), 0, stream>>>(W, Wt);
    // 128 b x 16 pair x 4 gq = 8192 blocks
    hydra_fused<<<dim3(CB * 16 * 4), dim3(256), 0, stream>>>(X, Wt, I, out);
}